// Round 6
// baseline (4503.441 us; speedup 1.0000x reference)
//
#include <hip/hip_runtime.h>
#include <cstdint>

#define HDIM   1536
#define DIN    256
#define NSTEP  1008     // (T-1)*B = 63*16
#define NWG    256
#define TPB    384      // 6 waves; wave w owns unit g*6+w in BOTH layers
#define UPW    6
#define NREP   8        // exchange replicas

// Exchange: one u32 per hidden unit: bf16 value | tag<<16 (self-tagged, tear-free).
// Region (layer, par) x NREP replicas, each 1536 u32.
// Producer phase p: h0(p) -> (0, p&1) tag p+1 ; h1(p-1) -> (1, (p+1)&1) tag p+1.
// Consumer phase n: h0(n-1) at (0,(n+1)&1) tag n ; h1(n-2) at (1, n&1) tag n.
// Column ownership: lane l consumes h-pairs 12l..12l+11 (units 24l..24l+23).
#define XBASE(layer, par, rep) ((((layer)*2 + (par))*NREP + (rep)) * 1536)
#define WS_FLAG_W (4*NREP*1536)   // 49152

typedef uint32_t u32x4v __attribute__((ext_vector_type(4)));
typedef uint32_t u32x2v __attribute__((ext_vector_type(2)));

__device__ __forceinline__ float bflo(uint32_t p){ union{uint32_t u; float f;} v; v.u = p << 16; return v.f; }
__device__ __forceinline__ float bfhi(uint32_t p){ union{uint32_t u; float f;} v; v.u = p & 0xffff0000u; return v.f; }
__device__ __forceinline__ float bf2f(uint16_t b){ union{uint32_t u; float f;} v; v.u = ((uint32_t)b) << 16; return v.f; }
__device__ __forceinline__ float fbits(uint32_t u){ union{uint32_t u; float f;} v; v.u = u; return v.f; }
__device__ __forceinline__ uint16_t f2bf(float f){
    union{float f; uint32_t u;} v; v.f = f;
    uint32_t r = v.u + 0x7fffu + ((v.u >> 16) & 1u);   // RNE
    return (uint16_t)(r >> 16);
}
__device__ __forceinline__ uint32_t packbf(float lo, float hi){
    return (uint32_t)f2bf(lo) | ((uint32_t)f2bf(hi) << 16);
}
// inf-safe fast tanh: 1 - 2/(e^{2x}+1)
__device__ __forceinline__ float tanh_fast(float x){
    return 1.f - 2.f/(__expf(2.f*x) + 1.f);
}

#if __has_builtin(__builtin_amdgcn_fdot2_f32_bf16)
typedef __bf16 bf16x2 __attribute__((ext_vector_type(2)));
__device__ __forceinline__ float dot2bf(uint32_t a, uint32_t b, float c){
    return __builtin_amdgcn_fdot2_f32_bf16(__builtin_bit_cast(bf16x2, a),
                                           __builtin_bit_cast(bf16x2, b), c, false);
}
#else
__device__ __forceinline__ float dot2bf(uint32_t a, uint32_t b, float c){
    c = fmaf(bflo(a), bflo(b), c);
    c = fmaf(bfhi(a), bfhi(b), c);
    return c;
}
#endif

__device__ __forceinline__ float wave_sum(float x){
    #pragma unroll
    for (int o = 1; o < 64; o <<= 1) x += __shfl_xor(x, o, 64);
    return x;
}

// issue a batch of 6 coherent dwordx4 loads (96 B per lane = this lane's 24 units)
// EARLY-CLOBBER outputs: loads must not alias the address pair.
#define ISSUE6(q0,q1,q2,q3,q4,q5,addr) \
    asm volatile("global_load_dwordx4 %0, %6, off sc0 sc1\n\t" \
                 "global_load_dwordx4 %1, %6, off offset:16 sc0 sc1\n\t" \
                 "global_load_dwordx4 %2, %6, off offset:32 sc0 sc1\n\t" \
                 "global_load_dwordx4 %3, %6, off offset:48 sc0 sc1\n\t" \
                 "global_load_dwordx4 %4, %6, off offset:64 sc0 sc1\n\t" \
                 "global_load_dwordx4 %5, %6, off offset:80 sc0 sc1" \
                 : "=&v"(q0),"=&v"(q1),"=&v"(q2),"=&v"(q3),"=&v"(q4),"=&v"(q5) \
                 : "v"(addr) : "memory")

// nonzero if any of the 4 hi16 tags in quad q mismatches want (want2 in scope)
#define TAG2(q) ((__builtin_amdgcn_perm((q).y,(q).x,0x07060302u)^want2) \
               | (__builtin_amdgcn_perm((q).w,(q).z,0x07060302u)^want2))

// quad m (units 4m..4m+3 of this lane) -> pairs 2m, 2m+1
#define PAIRS2(dst,m,q) do{ \
    (dst)[2*(m)]   = __builtin_amdgcn_perm((q).y,(q).x,0x05040100u); \
    (dst)[2*(m)+1] = __builtin_amdgcn_perm((q).w,(q).z,0x05040100u); }while(0)

#define WAITV(N) do{ asm volatile("s_waitcnt vmcnt(" #N ")" ::: "memory"); \
                     __builtin_amdgcn_sched_barrier(0); }while(0)

// ---------------------------------------------------------------------------
// init kernel: clear exchange (stale-tag kill), seed boot tags, dtype probe
// ---------------------------------------------------------------------------
__global__ void init_ws(const uint32_t* __restrict__ w, uint32_t* __restrict__ ws){
    const int i = blockIdx.x * blockDim.x + threadIdx.x;
    if (i < 4*NREP*1536){
        // region 3 = (layer1, par1): h1(-1) boot -> tag 1, value 0.
        // regions 0..2 cleared to tag 0 (h0(-1) and h1(-2) boots read tag 0 zeros).
        ws[i] = (i >= 3*NREP*1536) ? 0x00010000u : 0u;
    }
    if (blockIdx.x == 0 && threadIdx.x < 64){
        const int t = threadIdx.x;
        int cnt = 0;
        #pragma unroll
        for (int j = 0; j < 4; ++j){
            const uint32_t v = w[t*4 + j];
            const uint32_t e = (v >> 7) & 0xFFu;
            if (e == 0u || (e >= 0x70u && e <= 0x7Cu)) cnt++;
        }
        #pragma unroll
        for (int o = 1; o < 64; o <<= 1) cnt += __shfl_xor(cnt, o, 64);
        if (t == 0)
            ws[WS_FLAG_W] = (cnt < 128) ? 1u : 0u;   // sparse in-window => fp32
    }
}

__global__ __launch_bounds__(TPB, 1)
void lstm_seq_kernel(const void* __restrict__ batch_,
                     const void* __restrict__ Wih0_,
                     const void* __restrict__ Whh0_,
                     const void* __restrict__ bih0_,
                     const void* __restrict__ bhh0_,
                     const void* __restrict__ Wih1_,
                     const void* __restrict__ Whh1_,
                     const void* __restrict__ bih1_,
                     const void* __restrict__ bhh1_,
                     void* __restrict__ out_,
                     uint32_t* __restrict__ ws)
{
    __shared__ uint32_t lds_w[UPW*4*8*64];   // 48 KB: L1 Wih1 chunks 0..7, per-wave rows
    __shared__ uint32_t lds_h0[13*64];       // stride-13: conflict-free relay
    __shared__ uint32_t lds_h1[13*64];
    __shared__ int      lds_flag[2];

    const int g   = blockIdx.x;
    const int tid = threadIdx.x;
    const int w   = tid >> 6;        // wave 0..5
    const int l   = tid & 63;
    const int U   = g*UPW + w;       // owned hidden unit (both layers)
    const int rep = g & (NREP-1);

    const uint32_t fp32in = __hip_atomic_load(&ws[WS_FLAG_W],
                             __ATOMIC_RELAXED, __HIP_MEMORY_SCOPE_AGENT);

    if (tid < 2) lds_flag[tid] = -1;

    // ---------------- persistent weight load (once) ----------------
    // lane l owns h-pairs 12l+k (k<12) and x-pairs 2l, 2l+1
    uint32_t w0[4][14];   // L0: 2 x-chunks + 12 h-chunks
    uint32_t w1[4][16];   // L1: Wih1 chunks 8..11 + Whh1 chunks 0..11
    float bb0[4], bb1[4];

    if (fp32in){
        const float2* Wih0f = (const float2*)Wih0_;
        const float2* Whh0f = (const float2*)Whh0_;
        const float2* Wih1f = (const float2*)Wih1_;
        const float2* Whh1f = (const float2*)Whh1_;
        #pragma unroll
        for (int r = 0; r < 4; ++r){
            const int grow = r*HDIM + U;
            float2 t;
            t = Wih0f[grow*(DIN/2) + 2*l + 0]; w0[r][0] = packbf(t.x, t.y);
            t = Wih0f[grow*(DIN/2) + 2*l + 1]; w0[r][1] = packbf(t.x, t.y);
            #pragma unroll
            for (int k = 0; k < 12; ++k){
                t = Whh0f[grow*768 + 12*l + k]; w0[r][k+2] = packbf(t.x, t.y);
            }
            #pragma unroll
            for (int c = 0; c < 8; ++c){
                t = Wih1f[grow*768 + 12*l + c];
                lds_w[((w*4 + r)*8 + c)*64 + l] = packbf(t.x, t.y);
            }
            #pragma unroll
            for (int c = 8; c < 12; ++c){
                t = Wih1f[grow*768 + 12*l + c]; w1[r][c-8] = packbf(t.x, t.y);
            }
            #pragma unroll
            for (int k = 0; k < 12; ++k){
                t = Whh1f[grow*768 + 12*l + k]; w1[r][k+4] = packbf(t.x, t.y);
            }
            bb0[r] = ((const float*)bih0_)[grow] + ((const float*)bhh0_)[grow];
            bb1[r] = ((const float*)bih1_)[grow] + ((const float*)bhh1_)[grow];
        }
    } else {
        const uint32_t* Wih0p = (const uint32_t*)Wih0_;
        const uint32_t* Whh0p = (const uint32_t*)Whh0_;
        const uint32_t* Wih1p = (const uint32_t*)Wih1_;
        const uint32_t* Whh1p = (const uint32_t*)Whh1_;
        #pragma unroll
        for (int r = 0; r < 4; ++r){
            const int grow = r*HDIM + U;
            w0[r][0] = Wih0p[grow*(DIN/2) + 2*l + 0];
            w0[r][1] = Wih0p[grow*(DIN/2) + 2*l + 1];
            #pragma unroll
            for (int k = 0; k < 12; ++k) w0[r][k+2] = Whh0p[grow*768 + 12*l + k];
            #pragma unroll
            for (int c = 0; c < 8; ++c)
                lds_w[((w*4 + r)*8 + c)*64 + l] = Wih1p[grow*768 + 12*l + c];
            #pragma unroll
            for (int c = 8; c < 12; ++c) w1[r][c-8] = Wih1p[grow*768 + 12*l + c];
            #pragma unroll
            for (int k = 0; k < 12; ++k) w1[r][k+4] = Whh1p[grow*768 + 12*l + k];
            bb0[r] = bf2f(((const uint16_t*)bih0_)[grow]) + bf2f(((const uint16_t*)bhh0_)[grow]);
            bb1[r] = bf2f(((const uint16_t*)bih1_)[grow]) + bf2f(((const uint16_t*)bhh1_)[grow]);
        }
    }
    __syncthreads();   // lds_flag init + lds_w ready

    float cc0 = 0.f, cc1 = 0.f, h0f = 0.f, h1f = 0.f;

    for (int n = 0; n <= NSTEP; ++n){
        const uint32_t want  = (uint32_t)n;
        const uint32_t want2 = want | (want << 16);
        const int nn = (n < NSTEP) ? n : 0;
        const int xbase = ((nn & 15)*64 + (nn >> 4) + 1) * DIN;   // fp32 units

        uint32_t h0p[12], h1p[12];
        uint32_t xp0 = 0, xp1 = 0;

        if (w == 0){
            // ---- h0 poll: A/B rotation fully contained in this block ----
            // All in-flight asm registers are scoped HERE and drained (WAITV(0))
            // before leaving the block -- no in-flight register crosses compute.
            const uint32_t* b0 = ws + XBASE(0, (n+1) & 1, rep) + 24*l;
            u32x4v xq4; u32x2v xq2;
            u32x4v qa0,qa1,qa2,qa3,qa4,qa5, qb0,qb1,qb2,qb3,qb4,qb5;

            // issue x first (oldest), then A, then B: vmcnt arithmetic below
            // tolerates <=2 pending publish stores from the previous phase.
            if (fp32in){
                const char* xa = (const char*)batch_ + 4*(size_t)xbase + 16*l;
                asm volatile("global_load_dwordx4 %0, %1, off" : "=&v"(xq4) : "v"(xa) : "memory");
            } else {
                const char* xa = (const char*)batch_ + 2*(size_t)xbase + 8*l;
                asm volatile("global_load_dwordx2 %0, %1, off" : "=&v"(xq2) : "v"(xa) : "memory");
            }
            ISSUE6(qa0,qa1,qa2,qa3,qa4,qa5, b0);
            ISSUE6(qb0,qb1,qb2,qb3,qb4,qb5, b0);
            for (;;){
                WAITV(6);   // retires (stores+)x+A; leaves exactly B outstanding
                {
                    const uint32_t d = TAG2(qa0)|TAG2(qa1)|TAG2(qa2)|TAG2(qa3)|TAG2(qa4)|TAG2(qa5);
                    if (__all(d == 0u)){
                        PAIRS2(h0p,0,qa0); PAIRS2(h0p,1,qa1); PAIRS2(h0p,2,qa2);
                        PAIRS2(h0p,3,qa3); PAIRS2(h0p,4,qa4); PAIRS2(h0p,5,qa5);
                        break;
                    }
                }
                ISSUE6(qa0,qa1,qa2,qa3,qa4,qa5, b0);
                WAITV(6);   // retires B; leaves re-issued A outstanding
                {
                    const uint32_t d = TAG2(qb0)|TAG2(qb1)|TAG2(qb2)|TAG2(qb3)|TAG2(qb4)|TAG2(qb5);
                    if (__all(d == 0u)){
                        PAIRS2(h0p,0,qb0); PAIRS2(h0p,1,qb1); PAIRS2(h0p,2,qb2);
                        PAIRS2(h0p,3,qb3); PAIRS2(h0p,4,qb4); PAIRS2(h0p,5,qb5);
                        break;
                    }
                }
                ISSUE6(qb0,qb1,qb2,qb3,qb4,qb5, b0);
            }
            WAITV(0);   // drain loser NOW (fast path: issued ~20cy after winner => ~free)

            if (fp32in){ xp0 = packbf(fbits(xq4.x), fbits(xq4.y));
                         xp1 = packbf(fbits(xq4.z), fbits(xq4.w)); }
            else       { xp0 = xq2.x; xp1 = xq2.y; }

            // relay to other waves
            #pragma unroll
            for (int k = 0; k < 12; ++k) lds_h0[13*l + k] = h0p[k];
            __hip_atomic_store(&lds_flag[0], n, __ATOMIC_RELEASE, __HIP_MEMORY_SCOPE_WORKGROUP);
        } else {
            // x load (vectorized, plain)
            if (fp32in){
                const float4 t = ((const float4*)((const float*)batch_ + xbase))[l];
                xp0 = packbf(t.x, t.y); xp1 = packbf(t.z, t.w);
            } else {
                const uint2 t = ((const uint2*)((const uint16_t*)batch_ + xbase))[l];
                xp0 = t.x; xp1 = t.y;
            }
            if (w == 1){
                // ---- h1 poll: single-batch spin (full phase of slack) ----
                const uint32_t* b1 = ws + XBASE(1, n & 1, rep) + 24*l;
                u32x4v t0,t1,t2,t3,t4,t5;
                WAITV(0);
                for (;;){
                    ISSUE6(t0,t1,t2,t3,t4,t5, b1);
                    WAITV(0);
                    const uint32_t d = TAG2(t0)|TAG2(t1)|TAG2(t2)|TAG2(t3)|TAG2(t4)|TAG2(t5);
                    if (__all(d == 0u)) break;
                    __builtin_amdgcn_s_sleep(1);
                }
                PAIRS2(h1p,0,t0); PAIRS2(h1p,1,t1); PAIRS2(h1p,2,t2);
                PAIRS2(h1p,3,t3); PAIRS2(h1p,4,t4); PAIRS2(h1p,5,t5);
                #pragma unroll
                for (int k = 0; k < 12; ++k) lds_h1[13*l + k] = h1p[k];
                __hip_atomic_store(&lds_flag[1], n, __ATOMIC_RELEASE, __HIP_MEMORY_SCOPE_WORKGROUP);
            }
            // h0 via LDS relay
            while (__hip_atomic_load(&lds_flag[0], __ATOMIC_ACQUIRE, __HIP_MEMORY_SCOPE_WORKGROUP) < n)
                __builtin_amdgcn_s_sleep(1);
            #pragma unroll
            for (int k = 0; k < 12; ++k) h0p[k] = lds_h0[13*l + k];
        }

        // ---------------- layer 0 (the critical recurrence) ----------------
        if (n < NSTEP){
            __builtin_amdgcn_s_setprio(1);
            float acc[4];
            #pragma unroll
            for (int r = 0; r < 4; ++r){
                float a = dot2bf(w0[r][0], xp0, 0.f);
                a = dot2bf(w0[r][1], xp1, a);
                #pragma unroll
                for (int k = 0; k < 12; ++k) a = dot2bf(w0[r][k+2], h0p[k], a);
                acc[r] = a;
            }
            #pragma unroll
            for (int r = 0; r < 4; ++r) acc[r] = wave_sum(acc[r]);
            const float gi = acc[0] + bb0[0];
            const float gf = acc[1] + bb0[1];
            const float gg = acc[2] + bb0[2];
            const float go = acc[3] + bb0[3];
            const float si = 1.f/(1.f + __expf(-gi));
            const float sf = 1.f/(1.f + __expf(-gf));
            const float so = 1.f/(1.f + __expf(-go));
            cc0 = sf*cc0 + si*tanh_fast(gg);
            h0f = so*tanh_fast(cc0);
            __builtin_amdgcn_s_setprio(0);
            // immediate publish: h0f is wave-uniform; lanes 0..7 store the replicas
            const uint32_t pk = (uint32_t)f2bf(h0f) | ((uint32_t)(n + 1) << 16);
            if (l < NREP)
                __hip_atomic_store(ws + XBASE(0, n & 1, l) + U, pk,
                                   __ATOMIC_RELAXED, __HIP_MEMORY_SCOPE_AGENT);
        }

        // ---------------- layer 1 (rides in the shadow of the next hop) ----------------
        if (n >= 1){
            if (w != 1){
                while (__hip_atomic_load(&lds_flag[1], __ATOMIC_ACQUIRE, __HIP_MEMORY_SCOPE_WORKGROUP) < n)
                    __builtin_amdgcn_s_sleep(1);
                #pragma unroll
                for (int k = 0; k < 12; ++k) h1p[k] = lds_h1[13*l + k];
            }
            float acc[4];
            #pragma unroll
            for (int r = 0; r < 4; ++r){
                float a = 0.f;
                #pragma unroll
                for (int c = 0; c < 8; ++c)
                    a = dot2bf(lds_w[((w*4 + r)*8 + c)*64 + l], h0p[c], a);
                #pragma unroll
                for (int c = 8; c < 12; ++c) a = dot2bf(w1[r][c-8], h0p[c], a);
                #pragma unroll
                for (int k = 0; k < 12; ++k) a = dot2bf(w1[r][k+4], h1p[k], a);
                acc[r] = a;
            }
            #pragma unroll
            for (int r = 0; r < 4; ++r) acc[r] = wave_sum(acc[r]);
            const float gi = acc[0] + bb1[0];
            const float gf = acc[1] + bb1[1];
            const float gg = acc[2] + bb1[2];
            const float go = acc[3] + bb1[3];
            const float si = 1.f/(1.f + __expf(-gi));
            const float sf = 1.f/(1.f + __expf(-gf));
            const float so = 1.f/(1.f + __expf(-go));
            cc1 = sf*cc1 + si*tanh_fast(gg);
            h1f = so*tanh_fast(cc1);
            if (n < NSTEP){
                const uint32_t pk = (uint32_t)f2bf(h1f) | ((uint32_t)(n + 1) << 16);
                if (l < NREP)
                    __hip_atomic_store(ws + XBASE(1, (n+1) & 1, l) + U, pk,
                                       __ATOMIC_RELAXED, __HIP_MEMORY_SCOPE_AGENT);
            }
        }
    }

    // ---------------- output: h[2][1536] ++ c[2][1536] ----------------
    if (l == 0){
        if (fp32in){
            float* o = (float*)out_;
            o[U]               = h0f;
            o[HDIM + U]        = h1f;
            o[3072 + U]        = cc0;
            o[3072 + HDIM + U] = cc1;
        } else {
            uint16_t* o = (uint16_t*)out_;
            o[U]               = f2bf(h0f);
            o[HDIM + U]        = f2bf(h1f);
            o[3072 + U]        = f2bf(cc0);
            o[3072 + HDIM + U] = f2bf(cc1);
        }
    }
}

extern "C" void kernel_launch(void* const* d_in, const int* in_sizes, int n_in,
                              void* d_out, int out_size, void* d_ws, size_t ws_size,
                              hipStream_t stream)
{
    (void)in_sizes; (void)n_in; (void)out_size; (void)ws_size;
    const void* batch = d_in[0];
    const void* Wih0  = d_in[1];
    const void* Whh0  = d_in[2];
    const void* bih0  = d_in[3];
    const void* bhh0  = d_in[4];
    const void* Wih1  = d_in[5];
    const void* Whh1  = d_in[6];
    const void* bih1  = d_in[7];
    const void* bhh1  = d_in[8];
    void* out = d_out;
    uint32_t* ws = (uint32_t*)d_ws;

    hipLaunchKernelGGL(init_ws, dim3((4*NREP*1536 + 255)/256), dim3(256), 0, stream,
                       (const uint32_t*)Whh0, ws);

    void* args[] = { &batch, &Wih0, &Whh0, &bih0, &bhh0,
                     &Wih1, &Whh1, &bih1, &bhh1, &out, &ws };
    hipLaunchCooperativeKernel((const void*)lstm_seq_kernel,
                               dim3(NWG), dim3(TPB), args, 0, stream);
}

// Round 8
// 4365.572 us; speedup vs baseline: 1.0316x; 1.0316x over previous
//
#include <hip/hip_runtime.h>
#include <cstdint>

#define HDIM   1536
#define DIN    256
#define NSTEP  1008     // (T-1)*B = 63*16
#define NWG    256
#define TPB    384      // 6 waves; wave w owns unit g*6+w in BOTH layers
#define UPW    6
#define NREP   8        // exchange replicas

// Exchange: one u32 per hidden unit: bf16 value | tag<<16 (self-tagged, tear-free).
// Region (layer, par) x NREP replicas, each 1536 u32.
// Producer phase p: h0(p) -> (0, p&1) tag p+1 ; h1(p-1) -> (1, (p+1)&1) tag p+1.
// Consumer phase n: h0(n-1) at (0,(n+1)&1) tag n ; h1(n-2) at (1, n&1) tag n.
// Column ownership: lane l consumes h-pairs 12l..12l+11 (units 24l..24l+23).
#define XBASE(layer, par, rep) ((((layer)*2 + (par))*NREP + (rep)) * 1536)
#define WS_FLAG_W (4*NREP*1536)   // 49152

// watchdog caps: poll ~1 us/iter -> 64Ki ~ 65 ms; flag spin ~50 ns -> 1Mi ~ 50 ms.
// Normal waits are 3-10 iters; caps never fire in a healthy run. After a trip,
// 'bad' collapses caps to 1 so the kernel drains fast but keeps publishing.
#define WD_POLL (1 << 16)
#define WD_FLAG (1 << 20)

typedef uint32_t u32x4v __attribute__((ext_vector_type(4)));
typedef uint32_t u32x2v __attribute__((ext_vector_type(2)));

__device__ __forceinline__ float bflo(uint32_t p){ union{uint32_t u; float f;} v; v.u = p << 16; return v.f; }
__device__ __forceinline__ float bfhi(uint32_t p){ union{uint32_t u; float f;} v; v.u = p & 0xffff0000u; return v.f; }
__device__ __forceinline__ float bf2f(uint16_t b){ union{uint32_t u; float f;} v; v.u = ((uint32_t)b) << 16; return v.f; }
__device__ __forceinline__ uint16_t f2bf(float f){
    union{float f; uint32_t u;} v; v.f = f;
    uint32_t r = v.u + 0x7fffu + ((v.u >> 16) & 1u);   // RNE
    return (uint16_t)(r >> 16);
}
__device__ __forceinline__ uint32_t packbf(float lo, float hi){
    return (uint32_t)f2bf(lo) | ((uint32_t)f2bf(hi) << 16);
}
// inf-safe fast tanh: 1 - 2/(e^{2x}+1)
__device__ __forceinline__ float tanh_fast(float x){
    return 1.f - 2.f/(__expf(2.f*x) + 1.f);
}

#if __has_builtin(__builtin_amdgcn_fdot2_f32_bf16)
typedef __bf16 bf16x2 __attribute__((ext_vector_type(2)));
__device__ __forceinline__ float dot2bf(uint32_t a, uint32_t b, float c){
    return __builtin_amdgcn_fdot2_f32_bf16(__builtin_bit_cast(bf16x2, a),
                                           __builtin_bit_cast(bf16x2, b), c, false);
}
#else
__device__ __forceinline__ float dot2bf(uint32_t a, uint32_t b, float c){
    c = fmaf(bflo(a), bflo(b), c);
    c = fmaf(bfhi(a), bfhi(b), c);
    return c;
}
#endif

__device__ __forceinline__ float wave_sum(float x){
    #pragma unroll
    for (int o = 1; o < 64; o <<= 1) x += __shfl_xor(x, o, 64);
    return x;
}

// issue a batch of 6 coherent dwordx4 loads (96 B per lane = this lane's 24 units)
// EARLY-CLOBBER outputs: loads must not alias the address pair.
#define ISSUE6(q0,q1,q2,q3,q4,q5,addr) \
    asm volatile("global_load_dwordx4 %0, %6, off sc0 sc1\n\t" \
                 "global_load_dwordx4 %1, %6, off offset:16 sc0 sc1\n\t" \
                 "global_load_dwordx4 %2, %6, off offset:32 sc0 sc1\n\t" \
                 "global_load_dwordx4 %3, %6, off offset:48 sc0 sc1\n\t" \
                 "global_load_dwordx4 %4, %6, off offset:64 sc0 sc1\n\t" \
                 "global_load_dwordx4 %5, %6, off offset:80 sc0 sc1" \
                 : "=&v"(q0),"=&v"(q1),"=&v"(q2),"=&v"(q3),"=&v"(q4),"=&v"(q5) \
                 : "v"(addr) : "memory")

// nonzero if any of the 4 hi16 tags in quad q mismatches want (want2 in scope)
#define TAG2(q) ((__builtin_amdgcn_perm((q).y,(q).x,0x07060302u)^want2) \
               | (__builtin_amdgcn_perm((q).w,(q).z,0x07060302u)^want2))

// quad m (units 4m..4m+3 of this lane) -> pairs 2m, 2m+1
#define PAIRS2(dst,m,q) do{ \
    (dst)[2*(m)]   = __builtin_amdgcn_perm((q).y,(q).x,0x05040100u); \
    (dst)[2*(m)+1] = __builtin_amdgcn_perm((q).w,(q).z,0x05040100u); }while(0)

#define WAITV(N) do{ asm volatile("s_waitcnt vmcnt(" #N ")" ::: "memory"); \
                     __builtin_amdgcn_sched_barrier(0); }while(0)

// ---------------------------------------------------------------------------
// init kernel: clear exchange (stale-tag kill), seed boot tags, dtype probe
// ---------------------------------------------------------------------------
__global__ void init_ws(const uint32_t* __restrict__ w, uint32_t* __restrict__ ws){
    const int i = blockIdx.x * blockDim.x + threadIdx.x;
    if (i < 4*NREP*1536){
        // region 3 = (layer1, par1): h1(-1) boot -> tag 1, value 0.
        // regions 0..2 cleared to tag 0 (h0(-1) and h1(-2) boots read tag 0 zeros).
        ws[i] = (i >= 3*NREP*1536) ? 0x00010000u : 0u;
    }
    if (blockIdx.x == 0 && threadIdx.x < 64){
        const int t = threadIdx.x;
        int cnt = 0;
        #pragma unroll
        for (int j = 0; j < 4; ++j){
            const uint32_t v = w[t*4 + j];
            const uint32_t e = (v >> 7) & 0xFFu;
            if (e == 0u || (e >= 0x70u && e <= 0x7Cu)) cnt++;
        }
        #pragma unroll
        for (int o = 1; o < 64; o <<= 1) cnt += __shfl_xor(cnt, o, 64);
        if (t == 0)
            ws[WS_FLAG_W] = (cnt < 128) ? 1u : 0u;   // sparse in-window => fp32
    }
}

__global__ __launch_bounds__(TPB, 1)
void lstm_seq_kernel(const void* __restrict__ batch_,
                     const void* __restrict__ Wih0_,
                     const void* __restrict__ Whh0_,
                     const void* __restrict__ bih0_,
                     const void* __restrict__ bhh0_,
                     const void* __restrict__ Wih1_,
                     const void* __restrict__ Whh1_,
                     const void* __restrict__ bih1_,
                     const void* __restrict__ bhh1_,
                     void* __restrict__ out_,
                     uint32_t* __restrict__ ws)
{
    __shared__ uint32_t lds_w[UPW*4*8*64];   // 48 KB: L1 Wih1 chunks 0..7, per-wave rows
    __shared__ uint32_t lds_h0[13*64];       // stride-13: conflict-free relay
    __shared__ uint32_t lds_h1[13*64];
    __shared__ int      lds_flag[2];

    const int g   = blockIdx.x;
    const int tid = threadIdx.x;
    const int w   = tid >> 6;        // wave 0..5
    const int l   = tid & 63;
    const int U   = g*UPW + w;       // owned hidden unit (both layers)
    const int rep = g & (NREP-1);

    const uint32_t fp32in = __hip_atomic_load(&ws[WS_FLAG_W],
                             __ATOMIC_RELAXED, __HIP_MEMORY_SCOPE_AGENT);

    if (tid < 2) lds_flag[tid] = -1;

    // ---------------- persistent weight load (once) ----------------
    // lane l owns h-pairs 12l+k (k<12) and x-pairs 2l, 2l+1
    uint32_t w0[4][14];   // L0: 2 x-chunks + 12 h-chunks
    uint32_t w1[4][16];   // L1: Wih1 chunks 8..11 + Whh1 chunks 0..11
    float bb0[4], bb1[4];

    if (fp32in){
        const float2* Wih0f = (const float2*)Wih0_;
        const float2* Whh0f = (const float2*)Whh0_;
        const float2* Wih1f = (const float2*)Wih1_;
        const float2* Whh1f = (const float2*)Whh1_;
        #pragma unroll
        for (int r = 0; r < 4; ++r){
            const int grow = r*HDIM + U;
            float2 t;
            t = Wih0f[grow*(DIN/2) + 2*l + 0]; w0[r][0] = packbf(t.x, t.y);
            t = Wih0f[grow*(DIN/2) + 2*l + 1]; w0[r][1] = packbf(t.x, t.y);
            #pragma unroll
            for (int k = 0; k < 12; ++k){
                t = Whh0f[grow*768 + 12*l + k]; w0[r][k+2] = packbf(t.x, t.y);
            }
            #pragma unroll
            for (int c = 0; c < 8; ++c){
                t = Wih1f[grow*768 + 12*l + c];
                lds_w[((w*4 + r)*8 + c)*64 + l] = packbf(t.x, t.y);
            }
            #pragma unroll
            for (int c = 8; c < 12; ++c){
                t = Wih1f[grow*768 + 12*l + c]; w1[r][c-8] = packbf(t.x, t.y);
            }
            #pragma unroll
            for (int k = 0; k < 12; ++k){
                t = Whh1f[grow*768 + 12*l + k]; w1[r][k+4] = packbf(t.x, t.y);
            }
            bb0[r] = ((const float*)bih0_)[grow] + ((const float*)bhh0_)[grow];
            bb1[r] = ((const float*)bih1_)[grow] + ((const float*)bhh1_)[grow];
        }
    } else {
        const uint32_t* Wih0p = (const uint32_t*)Wih0_;
        const uint32_t* Whh0p = (const uint32_t*)Whh0_;
        const uint32_t* Wih1p = (const uint32_t*)Wih1_;
        const uint32_t* Whh1p = (const uint32_t*)Whh1_;
        #pragma unroll
        for (int r = 0; r < 4; ++r){
            const int grow = r*HDIM + U;
            w0[r][0] = Wih0p[grow*(DIN/2) + 2*l + 0];
            w0[r][1] = Wih0p[grow*(DIN/2) + 2*l + 1];
            #pragma unroll
            for (int k = 0; k < 12; ++k) w0[r][k+2] = Whh0p[grow*768 + 12*l + k];
            #pragma unroll
            for (int c = 0; c < 8; ++c)
                lds_w[((w*4 + r)*8 + c)*64 + l] = Wih1p[grow*768 + 12*l + c];
            #pragma unroll
            for (int c = 8; c < 12; ++c) w1[r][c-8] = Wih1p[grow*768 + 12*l + c];
            #pragma unroll
            for (int k = 0; k < 12; ++k) w1[r][k+4] = Whh1p[grow*768 + 12*l + k];
            bb0[r] = bf2f(((const uint16_t*)bih0_)[grow]) + bf2f(((const uint16_t*)bhh0_)[grow]);
            bb1[r] = bf2f(((const uint16_t*)bih1_)[grow]) + bf2f(((const uint16_t*)bhh1_)[grow]);
        }
    }
    __syncthreads();   // lds_flag init + lds_w ready

    float cc0 = 0.f, cc1 = 0.f, h0f = 0.f, h1f = 0.f;
    int bad = 0;   // watchdog latch: once set, all spin caps collapse to 1

    for (int n = 0; n <= NSTEP; ++n){
        const uint32_t want  = (uint32_t)n;
        const uint32_t want2 = want | (want << 16);
        const int nn = (n < NSTEP) ? n : 0;
        const int xbase = ((nn & 15)*64 + (nn >> 4) + 1) * DIN;   // fp32 units

        uint32_t h0p[12], h1p[12];
        uint32_t xp0 = 0, xp1 = 0;

        // x load (vectorized, plain; in flight during poll, compiler waits at use)
        float4 xf4; uint2 xu2;
        if (fp32in) xf4 = ((const float4*)((const float*)batch_ + xbase))[l];
        else        xu2 = ((const uint2*)((const uint16_t*)batch_ + xbase))[l];

        if (w == 0){
            // ---- h0 poll: single batch + sleep retry (R1-proven pacing) ----
            const uint32_t* b0 = ws + XBASE(0, (n+1) & 1, rep) + 24*l;
            u32x4v q0,q1,q2,q3,q4,q5;
            int tries = bad ? 1 : WD_POLL;
            for (;;){
                ISSUE6(q0,q1,q2,q3,q4,q5, b0);
                WAITV(0);
                const uint32_t d = TAG2(q0)|TAG2(q1)|TAG2(q2)|TAG2(q3)|TAG2(q4)|TAG2(q5);
                if (__all(d == 0u)) break;
                if (--tries <= 0){ bad = 1; break; }
                __builtin_amdgcn_s_sleep(1);
            }
            PAIRS2(h0p,0,q0); PAIRS2(h0p,1,q1); PAIRS2(h0p,2,q2);
            PAIRS2(h0p,3,q3); PAIRS2(h0p,4,q4); PAIRS2(h0p,5,q5);
            // relay to other waves (wave 0 consumes its registers directly)
            #pragma unroll
            for (int k = 0; k < 12; ++k) lds_h0[13*l + k] = h0p[k];
            __hip_atomic_store(&lds_flag[0], n, __ATOMIC_RELEASE, __HIP_MEMORY_SCOPE_WORKGROUP);
        } else {
            if (w == 1){
                // ---- h1 poll: single-batch spin (full phase of slack) ----
                const uint32_t* b1 = ws + XBASE(1, n & 1, rep) + 24*l;
                u32x4v t0,t1,t2,t3,t4,t5;
                int tries = bad ? 1 : WD_POLL;
                for (;;){
                    ISSUE6(t0,t1,t2,t3,t4,t5, b1);
                    WAITV(0);
                    const uint32_t d = TAG2(t0)|TAG2(t1)|TAG2(t2)|TAG2(t3)|TAG2(t4)|TAG2(t5);
                    if (__all(d == 0u)) break;
                    if (--tries <= 0){ bad = 1; break; }
                    __builtin_amdgcn_s_sleep(1);
                }
                PAIRS2(h1p,0,t0); PAIRS2(h1p,1,t1); PAIRS2(h1p,2,t2);
                PAIRS2(h1p,3,t3); PAIRS2(h1p,4,t4); PAIRS2(h1p,5,t5);
                #pragma unroll
                for (int k = 0; k < 12; ++k) lds_h1[13*l + k] = h1p[k];
                __hip_atomic_store(&lds_flag[1], n, __ATOMIC_RELEASE, __HIP_MEMORY_SCOPE_WORKGROUP);
            }
            // h0 via LDS relay (bounded spin)
            {
                int tries = bad ? 1 : WD_FLAG;
                while (__hip_atomic_load(&lds_flag[0], __ATOMIC_ACQUIRE, __HIP_MEMORY_SCOPE_WORKGROUP) < n){
                    if (--tries <= 0){ bad = 1; break; }
                    __builtin_amdgcn_s_sleep(1);
                }
            }
            #pragma unroll
            for (int k = 0; k < 12; ++k) h0p[k] = lds_h0[13*l + k];
        }

        if (fp32in){ xp0 = packbf(xf4.x, xf4.y); xp1 = packbf(xf4.z, xf4.w); }
        else       { xp0 = xu2.x;                xp1 = xu2.y; }

        // ---------------- layer 0 (the critical recurrence) ----------------
        if (n < NSTEP){
            __builtin_amdgcn_s_setprio(1);
            float acc[4];
            #pragma unroll
            for (int r = 0; r < 4; ++r){
                float a = dot2bf(w0[r][0], xp0, 0.f);
                a = dot2bf(w0[r][1], xp1, a);
                #pragma unroll
                for (int k = 0; k < 12; ++k) a = dot2bf(w0[r][k+2], h0p[k], a);
                acc[r] = a;
            }
            #pragma unroll
            for (int r = 0; r < 4; ++r) acc[r] = wave_sum(acc[r]);
            const float gi = acc[0] + bb0[0];
            const float gf = acc[1] + bb0[1];
            const float gg = acc[2] + bb0[2];
            const float go = acc[3] + bb0[3];
            const float si = 1.f/(1.f + __expf(-gi));
            const float sf = 1.f/(1.f + __expf(-gf));
            const float so = 1.f/(1.f + __expf(-go));
            cc0 = sf*cc0 + si*tanh_fast(gg);
            h0f = so*tanh_fast(cc0);
            __builtin_amdgcn_s_setprio(0);
            // immediate publish: h0f is wave-uniform; lanes 0..7 store the replicas
            const uint32_t pk = (uint32_t)f2bf(h0f) | ((uint32_t)(n + 1) << 16);
            if (l < NREP)
                __hip_atomic_store(ws + XBASE(0, n & 1, l) + U, pk,
                                   __ATOMIC_RELAXED, __HIP_MEMORY_SCOPE_AGENT);
        }

        // ---------------- layer 1 (rides in the shadow of the next hop) ----------------
        if (n >= 1){
            if (w != 1){
                int tries = bad ? 1 : WD_FLAG;
                while (__hip_atomic_load(&lds_flag[1], __ATOMIC_ACQUIRE, __HIP_MEMORY_SCOPE_WORKGROUP) < n){
                    if (--tries <= 0){ bad = 1; break; }
                    __builtin_amdgcn_s_sleep(1);
                }
                #pragma unroll
                for (int k = 0; k < 12; ++k) h1p[k] = lds_h1[13*l + k];
            }
            float acc[4];
            #pragma unroll
            for (int r = 0; r < 4; ++r){
                float a = 0.f;
                #pragma unroll
                for (int c = 0; c < 8; ++c)
                    a = dot2bf(lds_w[((w*4 + r)*8 + c)*64 + l], h0p[c], a);
                #pragma unroll
                for (int c = 8; c < 12; ++c) a = dot2bf(w1[r][c-8], h0p[c], a);
                #pragma unroll
                for (int k = 0; k < 12; ++k) a = dot2bf(w1[r][k+4], h1p[k], a);
                acc[r] = a;
            }
            #pragma unroll
            for (int r = 0; r < 4; ++r) acc[r] = wave_sum(acc[r]);
            const float gi = acc[0] + bb1[0];
            const float gf = acc[1] + bb1[1];
            const float gg = acc[2] + bb1[2];
            const float go = acc[3] + bb1[3];
            const float si = 1.f/(1.f + __expf(-gi));
            const float sf = 1.f/(1.f + __expf(-gf));
            const float so = 1.f/(1.f + __expf(-go));
            cc1 = sf*cc1 + si*tanh_fast(gg);
            h1f = so*tanh_fast(cc1);
            if (n < NSTEP){
                const uint32_t pk = (uint32_t)f2bf(h1f) | ((uint32_t)(n + 1) << 16);
                if (l < NREP)
                    __hip_atomic_store(ws + XBASE(1, (n+1) & 1, l) + U, pk,
                                       __ATOMIC_RELAXED, __HIP_MEMORY_SCOPE_AGENT);
            }
        }
    }

    // ---------------- output: h[2][1536] ++ c[2][1536] ----------------
    if (l == 0){
        if (fp32in){
            float* o = (float*)out_;
            o[U]               = h0f;
            o[HDIM + U]        = h1f;
            o[3072 + U]        = cc0;
            o[3072 + HDIM + U] = cc1;
        } else {
            uint16_t* o = (uint16_t*)out_;
            o[U]               = f2bf(h0f);
            o[HDIM + U]        = f2bf(h1f);
            o[3072 + U]        = f2bf(cc0);
            o[3072 + HDIM + U] = f2bf(cc1);
        }
    }
}

extern "C" void kernel_launch(void* const* d_in, const int* in_sizes, int n_in,
                              void* d_out, int out_size, void* d_ws, size_t ws_size,
                              hipStream_t stream)
{
    (void)in_sizes; (void)n_in; (void)out_size; (void)ws_size;
    const void* batch = d_in[0];
    const void* Wih0  = d_in[1];
    const void* Whh0  = d_in[2];
    const void* bih0  = d_in[3];
    const void* bhh0  = d_in[4];
    const void* Wih1  = d_in[5];
    const void* Whh1  = d_in[6];
    const void* bih1  = d_in[7];
    const void* bhh1  = d_in[8];
    void* out = d_out;
    uint32_t* ws = (uint32_t*)d_ws;

    hipLaunchKernelGGL(init_ws, dim3((4*NREP*1536 + 255)/256), dim3(256), 0, stream,
                       (const uint32_t*)Whh0, ws);

    void* args[] = { &batch, &Wih0, &Whh0, &bih0, &bhh0,
                     &Wih1, &Whh1, &bih1, &bhh1, &out, &ws };
    hipLaunchCooperativeKernel((const void*)lstm_seq_kernel,
                               dim3(NWG), dim3(TPB), args, 0, stream);
}

// Round 10
// 3726.160 us; speedup vs baseline: 1.2086x; 1.1716x over previous
//
#include <hip/hip_runtime.h>
#include <cstdint>

#define HDIM   1536
#define DIN    256
#define NSTEP  1008     // (T-1)*B = 63*16
#define NWG    256
#define TPB    384      // 6 waves; wave w owns unit g*6+w in BOTH layers
#define UPW    6
#define NREP   8        // exchange replicas

// Exchange: one u32 per hidden unit: bf16 value | tag<<16 (self-tagged, tear-free).
// Region (layer, par) x NREP replicas, each 1536 u32.
// Producer phase p: h0(p) -> (0, p&1) tag p+1 ; h1(p-1) -> (1, (p+1)&1) tag p+1.
// Consumer phase n: h0(n-1) at (0,(n+1)&1) tag n ; h1(n-2) at (1, n&1) tag n.
// Poll mapping (COALESCED, R1-proven): load k reads the contiguous 512B block
// [512k, 512k+512); lane l takes 8B at 8l -> lane l owns h-pairs {64k + l}.
#define XBASE(layer, par, rep) ((((layer)*2 + (par))*NREP + (rep)) * 1536)
#define WS_FLAG_W (4*NREP*1536)   // 49152

// watchdog caps: poll ~1 us/iter -> 64Ki ~ 65 ms; flag spin ~50 ns -> 1Mi ~ 50 ms.
// Normal waits are 3-10 iters; caps never fire in a healthy run. After a trip,
// 'bad' collapses caps to 1 so the kernel drains fast but keeps publishing.
#define WD_POLL (1 << 16)
#define WD_FLAG (1 << 20)

typedef uint32_t u32x2v __attribute__((ext_vector_type(2)));

__device__ __forceinline__ float bflo(uint32_t p){ union{uint32_t u; float f;} v; v.u = p << 16; return v.f; }
__device__ __forceinline__ float bfhi(uint32_t p){ union{uint32_t u; float f;} v; v.u = p & 0xffff0000u; return v.f; }
__device__ __forceinline__ float bf2f(uint16_t b){ union{uint32_t u; float f;} v; v.u = ((uint32_t)b) << 16; return v.f; }
__device__ __forceinline__ uint16_t f2bf(float f){
    union{float f; uint32_t u;} v; v.f = f;
    uint32_t r = v.u + 0x7fffu + ((v.u >> 16) & 1u);   // RNE
    return (uint16_t)(r >> 16);
}
__device__ __forceinline__ uint32_t packbf(float lo, float hi){
    return (uint32_t)f2bf(lo) | ((uint32_t)f2bf(hi) << 16);
}
// inf-safe fast tanh: 1 - 2/(e^{2x}+1)
__device__ __forceinline__ float tanh_fast(float x){
    return 1.f - 2.f/(__expf(2.f*x) + 1.f);
}

#if __has_builtin(__builtin_amdgcn_fdot2_f32_bf16)
typedef __bf16 bf16x2 __attribute__((ext_vector_type(2)));
__device__ __forceinline__ float dot2bf(uint32_t a, uint32_t b, float c){
    return __builtin_amdgcn_fdot2_f32_bf16(__builtin_bit_cast(bf16x2, a),
                                           __builtin_bit_cast(bf16x2, b), c, false);
}
#else
__device__ __forceinline__ float dot2bf(uint32_t a, uint32_t b, float c){
    c = fmaf(bflo(a), bflo(b), c);
    c = fmaf(bfhi(a), bfhi(b), c);
    return c;
}
#endif

__device__ __forceinline__ float wave_sum(float x){
    #pragma unroll
    for (int o = 1; o < 64; o <<= 1) x += __shfl_xor(x, o, 64);
    return x;
}

// 12 coherent dwordx2 loads; addr = a + 512k - 2816 (each instruction = one
// contiguous 512B block across the wave -> ~8 cache lines, fully coalesced).
#define ISSUE12(q0,q1,q2,q3,q4,q5,q6,q7,q8,q9,qa,qb,addr) \
    asm volatile("global_load_dwordx2 %0,  %12, off offset:-2816 sc0 sc1\n\t" \
                 "global_load_dwordx2 %1,  %12, off offset:-2304 sc0 sc1\n\t" \
                 "global_load_dwordx2 %2,  %12, off offset:-1792 sc0 sc1\n\t" \
                 "global_load_dwordx2 %3,  %12, off offset:-1280 sc0 sc1\n\t" \
                 "global_load_dwordx2 %4,  %12, off offset:-768 sc0 sc1\n\t" \
                 "global_load_dwordx2 %5,  %12, off offset:-256 sc0 sc1\n\t" \
                 "global_load_dwordx2 %6,  %12, off offset:256 sc0 sc1\n\t" \
                 "global_load_dwordx2 %7,  %12, off offset:768 sc0 sc1\n\t" \
                 "global_load_dwordx2 %8,  %12, off offset:1280 sc0 sc1\n\t" \
                 "global_load_dwordx2 %9,  %12, off offset:1792 sc0 sc1\n\t" \
                 "global_load_dwordx2 %10, %12, off offset:2304 sc0 sc1\n\t" \
                 "global_load_dwordx2 %11, %12, off offset:2816 sc0 sc1" \
                 : "=&v"(q0),"=&v"(q1),"=&v"(q2),"=&v"(q3),"=&v"(q4),"=&v"(q5), \
                   "=&v"(q6),"=&v"(q7),"=&v"(q8),"=&v"(q9),"=&v"(qa),"=&v"(qb) \
                 : "v"(addr) : "memory")

// nonzero if either hi16 tag in the u64 mismatches want (want2 in scope)
#define TAG1(q) (__builtin_amdgcn_perm((q).y,(q).x,0x07060302u)^want2)
// value pair: lo16(x) | lo16(y)<<16  == packed bf16x2 of units (2j, 2j+1)
#define PAIR1(q) __builtin_amdgcn_perm((q).y,(q).x,0x05040100u)

#define WAITV(N) do{ asm volatile("s_waitcnt vmcnt(" #N ")" ::: "memory"); \
                     __builtin_amdgcn_sched_barrier(0); }while(0)

// ---------------------------------------------------------------------------
// init kernel: clear exchange (stale-tag kill), seed boot tags, dtype probe
// ---------------------------------------------------------------------------
__global__ void init_ws(const uint32_t* __restrict__ w, uint32_t* __restrict__ ws){
    const int i = blockIdx.x * blockDim.x + threadIdx.x;
    if (i < 4*NREP*1536){
        // region 3 = (layer1, par1): h1(-1) boot -> tag 1, value 0.
        // regions 0..2 cleared to tag 0 (h0(-1) and h1(-2) boots read tag 0 zeros).
        ws[i] = (i >= 3*NREP*1536) ? 0x00010000u : 0u;
    }
    if (blockIdx.x == 0 && threadIdx.x < 64){
        const int t = threadIdx.x;
        int cnt = 0;
        #pragma unroll
        for (int j = 0; j < 4; ++j){
            const uint32_t v = w[t*4 + j];
            const uint32_t e = (v >> 7) & 0xFFu;
            if (e == 0u || (e >= 0x70u && e <= 0x7Cu)) cnt++;
        }
        #pragma unroll
        for (int o = 1; o < 64; o <<= 1) cnt += __shfl_xor(cnt, o, 64);
        if (t == 0)
            ws[WS_FLAG_W] = (cnt < 128) ? 1u : 0u;   // sparse in-window => fp32
    }
}

__global__ __launch_bounds__(TPB, 1)
void lstm_seq_kernel(const void* __restrict__ batch_,
                     const void* __restrict__ Wih0_,
                     const void* __restrict__ Whh0_,
                     const void* __restrict__ bih0_,
                     const void* __restrict__ bhh0_,
                     const void* __restrict__ Wih1_,
                     const void* __restrict__ Whh1_,
                     const void* __restrict__ bih1_,
                     const void* __restrict__ bhh1_,
                     void* __restrict__ out_,
                     uint32_t* __restrict__ ws)
{
    __shared__ uint32_t lds_w[UPW*4*8*64];   // 48 KB: L1 Wih1 chunks 0..7, per-wave rows
    __shared__ uint32_t lds_h0[13*64];       // stride-13: conflict-free relay
    __shared__ uint32_t lds_h1[13*64];
    __shared__ int      lds_flag[2];

    const int g   = blockIdx.x;
    const int tid = threadIdx.x;
    const int w   = tid >> 6;        // wave 0..5
    const int l   = tid & 63;
    const int U   = g*UPW + w;       // owned hidden unit (both layers)
    const int rep = g & (NREP-1);

    const uint32_t fp32in = __hip_atomic_load(&ws[WS_FLAG_W],
                             __ATOMIC_RELAXED, __HIP_MEMORY_SCOPE_AGENT);

    if (tid < 2) lds_flag[tid] = -1;

    // ---------------- persistent weight load (once) ----------------
    // lane l owns h-pairs {64k + l} (k<12) and x-pairs {2l, 2l+1}
    uint32_t w0[4][14];   // L0: 2 x-chunks + 12 h-chunks
    uint32_t w1[4][16];   // L1: Wih1 chunks 8..11 + Whh1 chunks 0..11
    float bb0[4], bb1[4];

    if (fp32in){
        const float2* Wih0f = (const float2*)Wih0_;
        const float2* Whh0f = (const float2*)Whh0_;
        const float2* Wih1f = (const float2*)Wih1_;
        const float2* Whh1f = (const float2*)Whh1_;
        #pragma unroll
        for (int r = 0; r < 4; ++r){
            const int grow = r*HDIM + U;
            float2 t;
            t = Wih0f[grow*(DIN/2) + 2*l + 0]; w0[r][0] = packbf(t.x, t.y);
            t = Wih0f[grow*(DIN/2) + 2*l + 1]; w0[r][1] = packbf(t.x, t.y);
            #pragma unroll
            for (int k = 0; k < 12; ++k){
                t = Whh0f[grow*768 + 64*k + l]; w0[r][k+2] = packbf(t.x, t.y);
            }
            #pragma unroll
            for (int c = 0; c < 8; ++c){
                t = Wih1f[grow*768 + 64*c + l];
                lds_w[((w*4 + r)*8 + c)*64 + l] = packbf(t.x, t.y);
            }
            #pragma unroll
            for (int c = 8; c < 12; ++c){
                t = Wih1f[grow*768 + 64*c + l]; w1[r][c-8] = packbf(t.x, t.y);
            }
            #pragma unroll
            for (int k = 0; k < 12; ++k){
                t = Whh1f[grow*768 + 64*k + l]; w1[r][k+4] = packbf(t.x, t.y);
            }
            bb0[r] = ((const float*)bih0_)[grow] + ((const float*)bhh0_)[grow];
            bb1[r] = ((const float*)bih1_)[grow] + ((const float*)bhh1_)[grow];
        }
    } else {
        const uint32_t* Wih0p = (const uint32_t*)Wih0_;
        const uint32_t* Whh0p = (const uint32_t*)Whh0_;
        const uint32_t* Wih1p = (const uint32_t*)Wih1_;
        const uint32_t* Whh1p = (const uint32_t*)Whh1_;
        #pragma unroll
        for (int r = 0; r < 4; ++r){
            const int grow = r*HDIM + U;
            w0[r][0] = Wih0p[grow*(DIN/2) + 2*l + 0];
            w0[r][1] = Wih0p[grow*(DIN/2) + 2*l + 1];
            #pragma unroll
            for (int k = 0; k < 12; ++k) w0[r][k+2] = Whh0p[grow*768 + 64*k + l];
            #pragma unroll
            for (int c = 0; c < 8; ++c)
                lds_w[((w*4 + r)*8 + c)*64 + l] = Wih1p[grow*768 + 64*c + l];
            #pragma unroll
            for (int c = 8; c < 12; ++c) w1[r][c-8] = Wih1p[grow*768 + 64*c + l];
            #pragma unroll
            for (int k = 0; k < 12; ++k) w1[r][k+4] = Whh1p[grow*768 + 64*k + l];
            bb0[r] = bf2f(((const uint16_t*)bih0_)[grow]) + bf2f(((const uint16_t*)bhh0_)[grow]);
            bb1[r] = bf2f(((const uint16_t*)bih1_)[grow]) + bf2f(((const uint16_t*)bhh1_)[grow]);
        }
    }
    __syncthreads();   // lds_flag init + lds_w ready

    float cc0 = 0.f, cc1 = 0.f, h0f = 0.f, h1f = 0.f;
    int bad = 0;   // watchdog latch: once set, all spin caps collapse to 1

    for (int n = 0; n <= NSTEP; ++n){
        const uint32_t want  = (uint32_t)n;
        const uint32_t want2 = want | (want << 16);
        const int nn = (n < NSTEP) ? n : 0;
        const int xbase = ((nn & 15)*64 + (nn >> 4) + 1) * DIN;   // fp32 units

        uint32_t h0p[12], h1p[12];
        uint32_t xp0 = 0, xp1 = 0;

        // x load (vectorized, plain; in flight during poll, compiler waits at use)
        float4 xf4; uint2 xu2;
        if (fp32in) xf4 = ((const float4*)((const float*)batch_ + xbase))[l];
        else        xu2 = ((const uint2*)((const uint16_t*)batch_ + xbase))[l];

        if (w == 0){
            // ---- h0 poll: single coalesced batch + backoff retry ----
            const char* a0 = (const char*)(ws + XBASE(0, (n+1) & 1, rep)) + 8*l + 2816;
            u32x2v q0,q1,q2,q3,q4,q5,q6,q7,q8,q9,qa,qb;
            int tries = bad ? 1 : WD_POLL;
            int first = 1;
            for (;;){
                ISSUE12(q0,q1,q2,q3,q4,q5,q6,q7,q8,q9,qa,qb, a0);
                WAITV(0);
                const uint32_t d = TAG1(q0)|TAG1(q1)|TAG1(q2)|TAG1(q3)|TAG1(q4)|TAG1(q5)
                                 | TAG1(q6)|TAG1(q7)|TAG1(q8)|TAG1(q9)|TAG1(qa)|TAG1(qb);
                if (__all(d == 0u)) break;
                if (--tries <= 0){ bad = 1; break; }
                if (first){ __builtin_amdgcn_s_sleep(8); first = 0; }
                else      { __builtin_amdgcn_s_sleep(2); }
            }
            h0p[0]=PAIR1(q0); h0p[1]=PAIR1(q1); h0p[2] =PAIR1(q2); h0p[3] =PAIR1(q3);
            h0p[4]=PAIR1(q4); h0p[5]=PAIR1(q5); h0p[6] =PAIR1(q6); h0p[7] =PAIR1(q7);
            h0p[8]=PAIR1(q8); h0p[9]=PAIR1(q9); h0p[10]=PAIR1(qa); h0p[11]=PAIR1(qb);
            // relay to other waves (wave 0 consumes its registers directly)
            #pragma unroll
            for (int k = 0; k < 12; ++k) lds_h0[13*l + k] = h0p[k];
            __hip_atomic_store(&lds_flag[0], n, __ATOMIC_RELEASE, __HIP_MEMORY_SCOPE_WORKGROUP);
        } else {
            if (w == 1){
                // ---- h1 poll: single coalesced batch (full phase of slack) ----
                const char* a1 = (const char*)(ws + XBASE(1, n & 1, rep)) + 8*l + 2816;
                u32x2v q0,q1,q2,q3,q4,q5,q6,q7,q8,q9,qa,qb;
                int tries = bad ? 1 : WD_POLL;
                for (;;){
                    ISSUE12(q0,q1,q2,q3,q4,q5,q6,q7,q8,q9,qa,qb, a1);
                    WAITV(0);
                    const uint32_t d = TAG1(q0)|TAG1(q1)|TAG1(q2)|TAG1(q3)|TAG1(q4)|TAG1(q5)
                                     | TAG1(q6)|TAG1(q7)|TAG1(q8)|TAG1(q9)|TAG1(qa)|TAG1(qb);
                    if (__all(d == 0u)) break;
                    if (--tries <= 0){ bad = 1; break; }
                    __builtin_amdgcn_s_sleep(2);
                }
                h1p[0]=PAIR1(q0); h1p[1]=PAIR1(q1); h1p[2] =PAIR1(q2); h1p[3] =PAIR1(q3);
                h1p[4]=PAIR1(q4); h1p[5]=PAIR1(q5); h1p[6] =PAIR1(q6); h1p[7] =PAIR1(q7);
                h1p[8]=PAIR1(q8); h1p[9]=PAIR1(q9); h1p[10]=PAIR1(qa); h1p[11]=PAIR1(qb);
                #pragma unroll
                for (int k = 0; k < 12; ++k) lds_h1[13*l + k] = h1p[k];
                __hip_atomic_store(&lds_flag[1], n, __ATOMIC_RELEASE, __HIP_MEMORY_SCOPE_WORKGROUP);
            }
            // h0 via LDS relay (bounded spin)
            {
                int tries = bad ? 1 : WD_FLAG;
                while (__hip_atomic_load(&lds_flag[0], __ATOMIC_ACQUIRE, __HIP_MEMORY_SCOPE_WORKGROUP) < n){
                    if (--tries <= 0){ bad = 1; break; }
                    __builtin_amdgcn_s_sleep(1);
                }
            }
            #pragma unroll
            for (int k = 0; k < 12; ++k) h0p[k] = lds_h0[13*l + k];
        }

        if (fp32in){ xp0 = packbf(xf4.x, xf4.y); xp1 = packbf(xf4.z, xf4.w); }
        else       { xp0 = xu2.x;                xp1 = xu2.y; }

        // ---------------- layer 0 (the critical recurrence) ----------------
        if (n < NSTEP){
            __builtin_amdgcn_s_setprio(1);
            float acc[4];
            #pragma unroll
            for (int r = 0; r < 4; ++r){
                float a = dot2bf(w0[r][0], xp0, 0.f);
                a = dot2bf(w0[r][1], xp1, a);
                #pragma unroll
                for (int k = 0; k < 12; ++k) a = dot2bf(w0[r][k+2], h0p[k], a);
                acc[r] = a;
            }
            #pragma unroll
            for (int r = 0; r < 4; ++r) acc[r] = wave_sum(acc[r]);
            const float gi = acc[0] + bb0[0];
            const float gf = acc[1] + bb0[1];
            const float gg = acc[2] + bb0[2];
            const float go = acc[3] + bb0[3];
            const float si = 1.f/(1.f + __expf(-gi));
            const float sf = 1.f/(1.f + __expf(-gf));
            const float so = 1.f/(1.f + __expf(-go));
            cc0 = sf*cc0 + si*tanh_fast(gg);
            h0f = so*tanh_fast(cc0);
            __builtin_amdgcn_s_setprio(0);
            // immediate publish: h0f is wave-uniform; lanes 0..7 store the replicas
            const uint32_t pk = (uint32_t)f2bf(h0f) | ((uint32_t)(n + 1) << 16);
            if (l < NREP)
                __hip_atomic_store(ws + XBASE(0, n & 1, l) + U, pk,
                                   __ATOMIC_RELAXED, __HIP_MEMORY_SCOPE_AGENT);
        }

        // ---------------- layer 1 (rides in the shadow of the next hop) ----------------
        if (n >= 1){
            if (w != 1){
                int tries = bad ? 1 : WD_FLAG;
                while (__hip_atomic_load(&lds_flag[1], __ATOMIC_ACQUIRE, __HIP_MEMORY_SCOPE_WORKGROUP) < n){
                    if (--tries <= 0){ bad = 1; break; }
                    __builtin_amdgcn_s_sleep(1);
                }
                #pragma unroll
                for (int k = 0; k < 12; ++k) h1p[k] = lds_h1[13*l + k];
            }
            float acc[4];
            #pragma unroll
            for (int r = 0; r < 4; ++r){
                float a = 0.f;
                #pragma unroll
                for (int c = 0; c < 8; ++c)
                    a = dot2bf(lds_w[((w*4 + r)*8 + c)*64 + l], h0p[c], a);
                #pragma unroll
                for (int c = 8; c < 12; ++c) a = dot2bf(w1[r][c-8], h0p[c], a);
                #pragma unroll
                for (int k = 0; k < 12; ++k) a = dot2bf(w1[r][k+4], h1p[k], a);
                acc[r] = a;
            }
            #pragma unroll
            for (int r = 0; r < 4; ++r) acc[r] = wave_sum(acc[r]);
            const float gi = acc[0] + bb1[0];
            const float gf = acc[1] + bb1[1];
            const float gg = acc[2] + bb1[2];
            const float go = acc[3] + bb1[3];
            const float si = 1.f/(1.f + __expf(-gi));
            const float sf = 1.f/(1.f + __expf(-gf));
            const float so = 1.f/(1.f + __expf(-go));
            cc1 = sf*cc1 + si*tanh_fast(gg);
            h1f = so*tanh_fast(cc1);
            if (n < NSTEP){
                const uint32_t pk = (uint32_t)f2bf(h1f) | ((uint32_t)(n + 1) << 16);
                if (l < NREP)
                    __hip_atomic_store(ws + XBASE(1, (n+1) & 1, l) + U, pk,
                                       __ATOMIC_RELAXED, __HIP_MEMORY_SCOPE_AGENT);
            }
        }
    }

    // ---------------- output: h[2][1536] ++ c[2][1536] ----------------
    if (l == 0){
        if (fp32in){
            float* o = (float*)out_;
            o[U]               = h0f;
            o[HDIM + U]        = h1f;
            o[3072 + U]        = cc0;
            o[3072 + HDIM + U] = cc1;
        } else {
            uint16_t* o = (uint16_t*)out_;
            o[U]               = f2bf(h0f);
            o[HDIM + U]        = f2bf(h1f);
            o[3072 + U]        = f2bf(cc0);
            o[3072 + HDIM + U] = f2bf(cc1);
        }
    }
}

extern "C" void kernel_launch(void* const* d_in, const int* in_sizes, int n_in,
                              void* d_out, int out_size, void* d_ws, size_t ws_size,
                              hipStream_t stream)
{
    (void)in_sizes; (void)n_in; (void)out_size; (void)ws_size;
    const void* batch = d_in[0];
    const void* Wih0  = d_in[1];
    const void* Whh0  = d_in[2];
    const void* bih0  = d_in[3];
    const void* bhh0  = d_in[4];
    const void* Wih1  = d_in[5];
    const void* Whh1  = d_in[6];
    const void* bih1  = d_in[7];
    const void* bhh1  = d_in[8];
    void* out = d_out;
    uint32_t* ws = (uint32_t*)d_ws;

    hipLaunchKernelGGL(init_ws, dim3((4*NREP*1536 + 255)/256), dim3(256), 0, stream,
                       (const uint32_t*)Whh0, ws);

    void* args[] = { &batch, &Wih0, &Whh0, &bih0, &bhh0,
                     &Wih1, &Whh1, &bih1, &bhh1, &out, &ws };
    hipLaunchCooperativeKernel((const void*)lstm_seq_kernel,
                               dim3(NWG), dim3(TPB), args, 0, stream);
}

// Round 11
// 3489.112 us; speedup vs baseline: 1.2907x; 1.0679x over previous
//
#include <hip/hip_runtime.h>
#include <cstdint>

#define HDIM   1536
#define DIN    256
#define NSTEP  1008     // (T-1)*B = 63*16
#define NWG    256
#define TPB    384      // 6 waves; wave w owns unit g*6+w in BOTH layers
#define UPW    6
#define NREP   8        // exchange replicas

// Exchange: one u32 per hidden unit: bf16 value | tag<<16.
// Per replica (u32 units): [h0 par0: 1536][h0 par1: 1536][h1 par0: 1536][h1 par1: 1536]
// Producer phase p: h0(p) -> parity p&1, tag p+1 ; h1(p-1) -> parity (p+1)&1, tag p+1.
// Consumer phase n: h0(n-1) at parity (n+1)&1 tag n ; h1(n-2) at parity n&1 tag n.
#define REP_W     6144
#define H1_OFF    3072
#define WS_FLAG_W (NREP*REP_W)   // 49152

typedef uint32_t u32x2 __attribute__((ext_vector_type(2)));

__device__ __forceinline__ float bflo(uint32_t p){ union{uint32_t u; float f;} v; v.u = p << 16; return v.f; }
__device__ __forceinline__ float bfhi(uint32_t p){ union{uint32_t u; float f;} v; v.u = p & 0xffff0000u; return v.f; }
__device__ __forceinline__ float bf2f(uint16_t b){ union{uint32_t u; float f;} v; v.u = ((uint32_t)b) << 16; return v.f; }
__device__ __forceinline__ uint16_t f2bf(float f){
    union{float f; uint32_t u;} v; v.f = f;
    uint32_t r = v.u + 0x7fffu + ((v.u >> 16) & 1u);   // RNE
    return (uint16_t)(r >> 16);
}
__device__ __forceinline__ uint32_t packbf(float lo, float hi){
    return (uint32_t)f2bf(lo) | ((uint32_t)f2bf(hi) << 16);
}
// inf-safe fast tanh: 1 - 2/(e^{2x}+1)
__device__ __forceinline__ float tanh_fast(float x){
    return 1.f - 2.f/(__expf(2.f*x) + 1.f);
}

#if __has_builtin(__builtin_amdgcn_fdot2_f32_bf16)
typedef __bf16 bf16x2 __attribute__((ext_vector_type(2)));
__device__ __forceinline__ float dot2bf(uint32_t a, uint32_t b, float c){
    return __builtin_amdgcn_fdot2_f32_bf16(__builtin_bit_cast(bf16x2, a),
                                           __builtin_bit_cast(bf16x2, b), c, false);
}
#else
__device__ __forceinline__ float dot2bf(uint32_t a, uint32_t b, float c){
    c = fmaf(bflo(a), bflo(b), c);
    c = fmaf(bfhi(a), bfhi(b), c);
    return c;
}
#endif

__device__ __forceinline__ float wave_sum(float x){
    #pragma unroll
    for (int o = 1; o < 64; o <<= 1) x += __shfl_xor(x, o, 64);
    return x;
}

// Poll 12 tagged u64 (24 tagged u32 values) from per-lane address a.
// addr_k = a + 512*k - 2816 ; success when ALL hi16 tags == want (wave-uniform loop).
// On success pr[k] = pair (lo16 of word0 | lo16 of word1 << 16).
template<int SLOW>
__device__ __forceinline__ void poll12(const char* a, uint32_t want, uint32_t pr[12]){
    u32x2 q0,q1,q2,q3,q4,q5,q6,q7,q8,q9,qa,qb;
    const uint32_t want2 = want | (want << 16);
    int t = 0;
    for (;;){
        asm volatile(
            "global_load_dwordx2 %0,  %12, off offset:-2816 sc0 sc1\n\t"
            "global_load_dwordx2 %1,  %12, off offset:-2304 sc0 sc1\n\t"
            "global_load_dwordx2 %2,  %12, off offset:-1792 sc0 sc1\n\t"
            "global_load_dwordx2 %3,  %12, off offset:-1280 sc0 sc1\n\t"
            "global_load_dwordx2 %4,  %12, off offset:-768 sc0 sc1\n\t"
            "global_load_dwordx2 %5,  %12, off offset:-256 sc0 sc1\n\t"
            "global_load_dwordx2 %6,  %12, off offset:256 sc0 sc1\n\t"
            "global_load_dwordx2 %7,  %12, off offset:768 sc0 sc1\n\t"
            "global_load_dwordx2 %8,  %12, off offset:1280 sc0 sc1\n\t"
            "global_load_dwordx2 %9,  %12, off offset:1792 sc0 sc1\n\t"
            "global_load_dwordx2 %10, %12, off offset:2304 sc0 sc1\n\t"
            "global_load_dwordx2 %11, %12, off offset:2816 sc0 sc1\n\t"
            "s_waitcnt vmcnt(0)"
            : "=v"(q0),"=v"(q1),"=v"(q2),"=v"(q3),"=v"(q4),"=v"(q5),
              "=v"(q6),"=v"(q7),"=v"(q8),"=v"(q9),"=v"(qa),"=v"(qb)
            : "v"(a) : "memory");
        uint32_t d;
        d  = __builtin_amdgcn_perm(q0.y, q0.x, 0x07060302u) ^ want2;
        d |= __builtin_amdgcn_perm(q1.y, q1.x, 0x07060302u) ^ want2;
        d |= __builtin_amdgcn_perm(q2.y, q2.x, 0x07060302u) ^ want2;
        d |= __builtin_amdgcn_perm(q3.y, q3.x, 0x07060302u) ^ want2;
        d |= __builtin_amdgcn_perm(q4.y, q4.x, 0x07060302u) ^ want2;
        d |= __builtin_amdgcn_perm(q5.y, q5.x, 0x07060302u) ^ want2;
        d |= __builtin_amdgcn_perm(q6.y, q6.x, 0x07060302u) ^ want2;
        d |= __builtin_amdgcn_perm(q7.y, q7.x, 0x07060302u) ^ want2;
        d |= __builtin_amdgcn_perm(q8.y, q8.x, 0x07060302u) ^ want2;
        d |= __builtin_amdgcn_perm(q9.y, q9.x, 0x07060302u) ^ want2;
        d |= __builtin_amdgcn_perm(qa.y, qa.x, 0x07060302u) ^ want2;
        d |= __builtin_amdgcn_perm(qb.y, qb.x, 0x07060302u) ^ want2;
        if (__all(d == 0u)) break;
        if (SLOW){
            if (t == 0) __builtin_amdgcn_s_sleep(8);
            else        __builtin_amdgcn_s_sleep(2);
        } else {
            __builtin_amdgcn_s_sleep(2);
        }
        ++t;
    }
    pr[0]  = __builtin_amdgcn_perm(q0.y, q0.x, 0x05040100u);
    pr[1]  = __builtin_amdgcn_perm(q1.y, q1.x, 0x05040100u);
    pr[2]  = __builtin_amdgcn_perm(q2.y, q2.x, 0x05040100u);
    pr[3]  = __builtin_amdgcn_perm(q3.y, q3.x, 0x05040100u);
    pr[4]  = __builtin_amdgcn_perm(q4.y, q4.x, 0x05040100u);
    pr[5]  = __builtin_amdgcn_perm(q5.y, q5.x, 0x05040100u);
    pr[6]  = __builtin_amdgcn_perm(q6.y, q6.x, 0x05040100u);
    pr[7]  = __builtin_amdgcn_perm(q7.y, q7.x, 0x05040100u);
    pr[8]  = __builtin_amdgcn_perm(q8.y, q8.x, 0x05040100u);
    pr[9]  = __builtin_amdgcn_perm(q9.y, q9.x, 0x05040100u);
    pr[10] = __builtin_amdgcn_perm(qa.y, qa.x, 0x05040100u);
    pr[11] = __builtin_amdgcn_perm(qb.y, qb.x, 0x05040100u);
}

// ---------------------------------------------------------------------------
// init kernel: full clear of exchange region (kills stale tags from prior
// dispatch), seed h1 parity-1 boot tag, dtype probe.
// ---------------------------------------------------------------------------
__global__ void init_ws(const uint32_t* __restrict__ w, uint32_t* __restrict__ ws){
    const int i = blockIdx.x * blockDim.x + threadIdx.x;
    if (i < NREP*REP_W){
        const int j = i % REP_W;
        ws[i] = (j >= H1_OFF + 1536) ? 0x00010000u : 0u;   // h1(-1): tag 1, zeros
    }
    if (blockIdx.x == 0 && threadIdx.x < 64){
        const int t = threadIdx.x;
        int cnt = 0;
        #pragma unroll
        for (int j = 0; j < 4; ++j){
            const uint32_t v = w[t*4 + j];
            const uint32_t e = (v >> 7) & 0xFFu;
            if (e == 0u || (e >= 0x70u && e <= 0x7Cu)) cnt++;
        }
        #pragma unroll
        for (int o = 1; o < 64; o <<= 1) cnt += __shfl_xor(cnt, o, 64);
        if (t == 0)
            ws[WS_FLAG_W] = (cnt < 128) ? 1u : 0u;   // sparse in-window => fp32
    }
}

__global__ __launch_bounds__(TPB, 1)
void lstm_seq_kernel(const void* __restrict__ batch_,
                     const void* __restrict__ Wih0_,
                     const void* __restrict__ Whh0_,
                     const void* __restrict__ bih0_,
                     const void* __restrict__ bhh0_,
                     const void* __restrict__ Wih1_,
                     const void* __restrict__ Whh1_,
                     const void* __restrict__ bih1_,
                     const void* __restrict__ bhh1_,
                     void* __restrict__ out_,
                     uint32_t* __restrict__ ws)
{
    __shared__ uint32_t lds_w[UPW*4*8*64];   // L1 chunks 0..7 per owned row
    __shared__ uint32_t lds_h0[768];         // packed h0 pairs (wave0-written)
    __shared__ uint32_t lds_h1[768];         // packed h1 pairs (wave1-written)
    __shared__ int      lds_flag[2];

    const int g   = blockIdx.x;
    const int tid = threadIdx.x;
    const int w   = tid >> 6;        // wave 0..5
    const int l   = tid & 63;
    const int U   = g*UPW + w;       // owned hidden unit (both layers)

    const uint32_t fp32in = __hip_atomic_load(&ws[WS_FLAG_W],
                             __ATOMIC_RELAXED, __HIP_MEMORY_SCOPE_AGENT);

    if (tid < 2) lds_flag[tid] = -1;

    // ---------------- persistent weight load (once) ----------------
    uint32_t w0[4][14];   // L0 rows of unit U: 2 x-chunks + 12 h-chunks
    uint32_t w1[4][16];   // L1 rows: chunks 8..11 (W_ih1) + 12..23 (W_hh1)
    float bb0[4], bb1[4];

    if (fp32in){
        const float2* Wih0f = (const float2*)Wih0_;
        const float2* Whh0f = (const float2*)Whh0_;
        const float2* Wih1f = (const float2*)Wih1_;
        const float2* Whh1f = (const float2*)Whh1_;
        #pragma unroll
        for (int r = 0; r < 4; ++r){
            const int grow = r*HDIM + U;
            float2 t;
            t = Wih0f[grow*(DIN/2) + l];      w0[r][0] = packbf(t.x, t.y);
            t = Wih0f[grow*(DIN/2) + 64 + l]; w0[r][1] = packbf(t.x, t.y);
            #pragma unroll
            for (int c = 0; c < 12; ++c){
                t = Whh0f[grow*(HDIM/2) + c*64 + l]; w0[r][c+2] = packbf(t.x, t.y);
            }
            #pragma unroll
            for (int c = 0; c < 8; ++c){
                t = Wih1f[grow*(HDIM/2) + c*64 + l];
                lds_w[(w*4 + r)*512 + c*64 + l] = packbf(t.x, t.y);
            }
            #pragma unroll
            for (int c = 8; c < 12; ++c){
                t = Wih1f[grow*(HDIM/2) + c*64 + l]; w1[r][c-8] = packbf(t.x, t.y);
            }
            #pragma unroll
            for (int c = 0; c < 12; ++c){
                t = Whh1f[grow*(HDIM/2) + c*64 + l]; w1[r][c+4] = packbf(t.x, t.y);
            }
            bb0[r] = ((const float*)bih0_)[grow] + ((const float*)bhh0_)[grow];
            bb1[r] = ((const float*)bih1_)[grow] + ((const float*)bhh1_)[grow];
        }
    } else {
        const uint32_t* Wih0p = (const uint32_t*)Wih0_;
        const uint32_t* Whh0p = (const uint32_t*)Whh0_;
        const uint32_t* Wih1p = (const uint32_t*)Wih1_;
        const uint32_t* Whh1p = (const uint32_t*)Whh1_;
        #pragma unroll
        for (int r = 0; r < 4; ++r){
            const int grow = r*HDIM + U;
            w0[r][0] = Wih0p[grow*(DIN/2) + l];
            w0[r][1] = Wih0p[grow*(DIN/2) + 64 + l];
            #pragma unroll
            for (int c = 0; c < 12; ++c) w0[r][c+2] = Whh0p[grow*(HDIM/2) + c*64 + l];
            #pragma unroll
            for (int c = 0; c < 8; ++c)
                lds_w[(w*4 + r)*512 + c*64 + l] = Wih1p[grow*(HDIM/2) + c*64 + l];
            #pragma unroll
            for (int c = 8; c < 12; ++c) w1[r][c-8] = Wih1p[grow*(HDIM/2) + c*64 + l];
            #pragma unroll
            for (int c = 0; c < 12; ++c) w1[r][c+4] = Whh1p[grow*(HDIM/2) + c*64 + l];
            bb0[r] = bf2f(((const uint16_t*)bih0_)[grow]) + bf2f(((const uint16_t*)bhh0_)[grow]);
            bb1[r] = bf2f(((const uint16_t*)bih1_)[grow]) + bf2f(((const uint16_t*)bhh1_)[grow]);
        }
    }
    __syncthreads();   // lds_flag init only; no barriers in the main loop

    float c0 = 0.f, c1 = 0.f, h0f = 0.f, h1f = 0.f;
    uint32_t* wsrep = ws + (g & (NREP-1))*REP_W;

    for (int n = 0; n <= NSTEP; ++n){
        // x prefetch (issued before any spinning)
        uint32_t xp0 = 0, xp1 = 0;
        if (n < NSTEP){
            const int xbase = ((n & 15)*64 + (n >> 4) + 1) * DIN;
            if (fp32in){
                const float2* bp = (const float2*)((const float*)batch_ + xbase);
                const float2 t0 = bp[l];
                const float2 t1 = bp[64 + l];
                xp0 = packbf(t0.x, t0.y); xp1 = packbf(t1.x, t1.y);
            } else {
                const uint32_t* bp = (const uint32_t*)batch_ + (xbase >> 1);
                xp0 = bp[l]; xp1 = bp[64 + l];
            }
        }

        uint32_t h0p[12];
        uint32_t h1p[12];

        // wave 1: EARLY h1 ingest (h1(n-2) was published last phase; ~1 sweep)
        if (w == 1 && n >= 1){
            const char* a = (const char*)(wsrep + H1_OFF + (n & 1)*1536) + 8*l + 2816;
            poll12<0>(a, (uint32_t)n, h1p);
            #pragma unroll
            for (int k = 0; k < 12; ++k) lds_h1[k*64 + l] = h1p[k];
            __hip_atomic_store(&lds_flag[1], n, __ATOMIC_RELEASE, __HIP_MEMORY_SCOPE_WORKGROUP);
        }

        // h0 ingest: wave 0 polls LLC, others take LDS rebroadcast
        if (w == 0){
            const char* a = (const char*)(wsrep + ((n+1) & 1)*1536) + 8*l + 2816;
            poll12<1>(a, (uint32_t)n, h0p);
            #pragma unroll
            for (int k = 0; k < 12; ++k) lds_h0[k*64 + l] = h0p[k];
            __hip_atomic_store(&lds_flag[0], n, __ATOMIC_RELEASE, __HIP_MEMORY_SCOPE_WORKGROUP);
        } else {
            while (__hip_atomic_load(&lds_flag[0], __ATOMIC_ACQUIRE, __HIP_MEMORY_SCOPE_WORKGROUP) < n)
                __builtin_amdgcn_s_sleep(1);
            #pragma unroll
            for (int k = 0; k < 12; ++k) h0p[k] = lds_h0[k*64 + l];
        }

        // ---------------- layer 0 (the critical recurrence) ----------------
        if (n < NSTEP){
            __builtin_amdgcn_s_setprio(1);
            float acc[4];
            #pragma unroll
            for (int r = 0; r < 4; ++r){
                float a = dot2bf(w0[r][0], xp0, 0.f);
                a = dot2bf(w0[r][1], xp1, a);
                #pragma unroll
                for (int k = 0; k < 12; ++k) a = dot2bf(w0[r][k+2], h0p[k], a);
                acc[r] = a;
            }
            #pragma unroll
            for (int r = 0; r < 4; ++r) acc[r] = wave_sum(acc[r]);
            const float gi = acc[0] + bb0[0];
            const float gf = acc[1] + bb0[1];
            const float gg = acc[2] + bb0[2];
            const float go = acc[3] + bb0[3];
            const float si = 1.f/(1.f + __expf(-gi));
            const float sf = 1.f/(1.f + __expf(-gf));
            const float so = 1.f/(1.f + __expf(-go));
            c0  = sf*c0 + si*tanh_fast(gg);
            h0f = so*tanh_fast(c0);
            // publish h0(n) immediately: parity n&1, tag n+1, all replicas
            const uint32_t pk = (uint32_t)f2bf(h0f) | ((uint32_t)(n + 1) << 16);
            if (l < NREP)
                __hip_atomic_store(ws + l*REP_W + (n & 1)*1536 + U, pk,
                                   __ATOMIC_RELAXED, __HIP_MEMORY_SCOPE_AGENT);
            __builtin_amdgcn_s_setprio(0);
        }

        // ---------------- layer 1 (trails with a phase of slack) ----------------
        if (n >= 1){
            if (w != 1){
                while (__hip_atomic_load(&lds_flag[1], __ATOMIC_ACQUIRE, __HIP_MEMORY_SCOPE_WORKGROUP) < n)
                    __builtin_amdgcn_s_sleep(1);
                #pragma unroll
                for (int k = 0; k < 12; ++k) h1p[k] = lds_h1[k*64 + l];
            }
            float acc[4];
            #pragma unroll
            for (int r = 0; r < 4; ++r){
                float a = 0.f;
                #pragma unroll
                for (int c = 0; c < 8; ++c)
                    a = dot2bf(lds_w[(w*4 + r)*512 + c*64 + l], h0p[c], a);
                #pragma unroll
                for (int c = 8; c < 12; ++c) a = dot2bf(w1[r][c-8], h0p[c], a);
                #pragma unroll
                for (int k = 0; k < 12; ++k) a = dot2bf(w1[r][k+4], h1p[k], a);
                acc[r] = a;
            }
            #pragma unroll
            for (int r = 0; r < 4; ++r) acc[r] = wave_sum(acc[r]);
            const float gi = acc[0] + bb1[0];
            const float gf = acc[1] + bb1[1];
            const float gg = acc[2] + bb1[2];
            const float go = acc[3] + bb1[3];
            const float si = 1.f/(1.f + __expf(-gi));
            const float sf = 1.f/(1.f + __expf(-gf));
            const float so = 1.f/(1.f + __expf(-go));
            c1  = sf*c1 + si*tanh_fast(gg);
            h1f = so*tanh_fast(c1);
            if (n < NSTEP){
                const uint32_t pk = (uint32_t)f2bf(h1f) | ((uint32_t)(n + 1) << 16);
                if (l < NREP)
                    __hip_atomic_store(ws + l*REP_W + H1_OFF + ((n+1) & 1)*1536 + U, pk,
                                       __ATOMIC_RELAXED, __HIP_MEMORY_SCOPE_AGENT);
            }
        }
    }

    // ---------------- output: h[2][1536] ++ c[2][1536] ----------------
    if (l == 0){
        if (fp32in){
            float* o = (float*)out_;
            o[U]               = h0f;
            o[HDIM + U]        = h1f;
            o[3072 + U]        = c0;
            o[3072 + HDIM + U] = c1;
        } else {
            uint16_t* o = (uint16_t*)out_;
            o[U]               = f2bf(h0f);
            o[HDIM + U]        = f2bf(h1f);
            o[3072 + U]        = f2bf(c0);
            o[3072 + HDIM + U] = f2bf(c1);
        }
    }
}

extern "C" void kernel_launch(void* const* d_in, const int* in_sizes, int n_in,
                              void* d_out, int out_size, void* d_ws, size_t ws_size,
                              hipStream_t stream)
{
    (void)in_sizes; (void)n_in; (void)out_size; (void)ws_size;
    const void* batch = d_in[0];
    const void* Wih0  = d_in[1];
    const void* Whh0  = d_in[2];
    const void* bih0  = d_in[3];
    const void* bhh0  = d_in[4];
    const void* Wih1  = d_in[5];
    const void* Whh1  = d_in[6];
    const void* bih1  = d_in[7];
    const void* bhh1  = d_in[8];
    void* out = d_out;
    uint32_t* ws = (uint32_t*)d_ws;

    hipLaunchKernelGGL(init_ws, dim3((NREP*REP_W + 255)/256), dim3(256), 0, stream,
                       (const uint32_t*)Whh0, ws);

    void* args[] = { &batch, &Wih0, &Whh0, &bih0, &bhh0,
                     &Wih1, &Whh1, &bih1, &bhh1, &out, &ws };
    hipLaunchCooperativeKernel((const void*)lstm_seq_kernel,
                               dim3(NWG), dim3(TPB), args, 0, stream);
}